// Round 1
// baseline (72.799 us; speedup 1.0000x reference)
//
#include <hip/hip_runtime.h>

#define K 5
#define N_ 8
#define C_ 256
#define H_ 64
#define W_ 64
#define HO 128
#define WO 128
#define HB 4            // base rows per block
#define WB 32           // base cols per block
#define CCHUNK 64
#define LDS_R (HB + K - 1)   // 8
#define LDS_C (WB + K - 1)   // 36

__global__ __launch_bounds__(256, 4)
void carafe_up_kernel(const float* __restrict__ feat,
                      const float* __restrict__ mask,
                      float* __restrict__ out) {
    const int wt = blockIdx.x;           // 0..1   (W tile)
    const int ht = blockIdx.y;           // 0..15  (H tile)
    const int zc = blockIdx.z;           // 0..31  (n * 4 + cchunk)
    const int n  = zc >> 2;
    const int c0 = (zc & 3) * CCHUNK;
    const int h0 = ht * HB;
    const int w0 = wt * WB;

    const int tid        = threadIdx.x;
    const int wlocal_out = tid & 63;     // output col within tile (0..63)
    const int h_local    = tid >> 6;     // base row within tile (0..3)
    const int w_local    = wlocal_out >> 1;
    const int Wg         = w0 * 2 + wlocal_out;     // global output col
    const int Hg0        = (h0 + h_local) * 2;      // global output row, a=0

    // Load the 2x25 mask values for this output-pixel pair ONCE (channel-invariant).
    float m0[K * K], m1[K * K];
    const float* mbase = mask + (size_t)n * (K * K) * (HO * WO)
                              + (size_t)Hg0 * WO + Wg;
    #pragma unroll
    for (int i = 0; i < K * K; ++i) {
        m0[i] = mbase[(size_t)i * (HO * WO)];
        m1[i] = mbase[(size_t)i * (HO * WO) + WO];
    }

    __shared__ float lds[2][LDS_R][LDS_C];

    const float* fbase = feat + (size_t)n * C_ * (H_ * W_);
    float*       obase = out  + (size_t)n * C_ * (HO * WO);

    auto stage = [&](int buf, int c) {
        const float* fc = fbase + (size_t)c * (H_ * W_);
        #pragma unroll
        for (int base = 0; base < LDS_R * LDS_C; base += 256) {
            int idx = base + tid;
            if (idx < LDS_R * LDS_C) {
                int r  = idx / LDS_C;
                int cc = idx - r * LDS_C;
                int hs = h0 - 2 + r;
                int ws = w0 - 2 + cc;
                float v = 0.f;
                if (hs >= 0 && hs < H_ && ws >= 0 && ws < W_)
                    v = fc[hs * W_ + ws];
                lds[buf][r][cc] = v;
            }
        }
    };

    stage(0, c0);
    for (int c = c0; c < c0 + CCHUNK; ++c) {
        __syncthreads();
        const int buf = c & 1;
        if (c + 1 < c0 + CCHUNK) stage(buf ^ 1, c + 1);

        float acc0 = 0.f, acc1 = 0.f;
        #pragma unroll
        for (int ki = 0; ki < K; ++ki) {
            #pragma unroll
            for (int kj = 0; kj < K; ++kj) {
                float f = lds[buf][h_local + ki][w_local + kj];
                acc0 = fmaf(f, m0[ki * K + kj], acc0);
                acc1 = fmaf(f, m1[ki * K + kj], acc1);
            }
        }
        float* oc = obase + (size_t)c * (HO * WO) + (size_t)Hg0 * WO + Wg;
        oc[0]  = acc0;
        oc[WO] = acc1;
    }
}

extern "C" void kernel_launch(void* const* d_in, const int* in_sizes, int n_in,
                              void* d_out, int out_size, void* d_ws, size_t ws_size,
                              hipStream_t stream) {
    const float* feat = (const float*)d_in[0];
    const float* mask = (const float*)d_in[1];
    float* out = (float*)d_out;

    dim3 grid(WO / (2 * WB), (HO / 2) / HB, N_ * (C_ / CCHUNK));  // (2, 16, 32)
    dim3 block(256);
    carafe_up_kernel<<<grid, block, 0, stream>>>(feat, mask, out);
}

// Round 2
// 53.738 us; speedup vs baseline: 1.3547x; 1.3547x over previous
//
#include <hip/hip_runtime.h>

#define K 5
#define N_ 8
#define C_ 256
#define H_ 64
#define W_ 64
#define HW (H_ * W_)
#define HO 128
#define WO 128
#define HB 4              // base rows per block
#define WB 32             // base cols per block
#define CCHUNK 32         // channels per block
#define UC 8              // channels per stage group
#define NGROUP (CCHUNK / UC)      // 4
#define LDS_R (HB + K - 1)        // 8
#define LDS_C (WB + K - 1)        // 36
#define CH_ELEMS (LDS_R * LDS_C)  // 288
#define SLAB (UC * CH_ELEMS)      // 2304 = 9 * 256
#define NLOAD (SLAB / 256)        // 9

__global__ __launch_bounds__(256)
void carafe_up_kernel(const float* __restrict__ feat,
                      const float* __restrict__ mask,
                      float* __restrict__ out) {
    const int wt = blockIdx.x;           // 0..1   (W tile)
    const int ht = blockIdx.y;           // 0..15  (H tile)
    const int zc = blockIdx.z;           // 0..63  (n * 8 + chunk)
    const int n  = zc >> 3;
    const int c0 = (zc & 7) * CCHUNK;
    const int h0 = ht * HB;
    const int w0 = wt * WB;

    const int tid        = threadIdx.x;
    const int wlocal_out = tid & 63;     // output col within tile (0..63)
    const int h_local    = tid >> 6;     // base row within tile (0..3)
    const int w_local    = wlocal_out >> 1;
    const int Wg         = w0 * 2 + wlocal_out;     // global output col
    const int Hg0        = (h0 + h_local) * 2;      // global output row, a=0

    // Channel-invariant masks for this thread's two output pixels: load once.
    float m0[K * K], m1[K * K];
    const float* mbase = mask + (size_t)n * (K * K) * (HO * WO)
                              + (size_t)Hg0 * WO + Wg;
    #pragma unroll
    for (int i = 0; i < K * K; ++i) {
        m0[i] = mbase[(size_t)i * (HO * WO)];
        m1[i] = mbase[(size_t)i * (HO * WO) + WO];
    }

    // Precompute per-thread staging offsets (flat idx -> (u, r, c)) once.
    int  off[NLOAD];
    bool valid[NLOAD];
    #pragma unroll
    for (int k = 0; k < NLOAD; ++k) {
        int idx = tid + k * 256;
        int u   = idx / CH_ELEMS;
        int rem = idx - u * CH_ELEMS;
        int r   = rem / LDS_C;
        int cc  = rem - r * LDS_C;
        int hs  = h0 - 2 + r;
        int ws  = w0 - 2 + cc;
        valid[k] = (hs >= 0 && hs < H_ && ws >= 0 && ws < W_);
        off[k]   = u * HW + hs * W_ + ws;
    }

    __shared__ float lds[2][SLAB];

    const float* fbase = feat + (size_t)n * C_ * HW;
    float*       obase = out  + (size_t)n * C_ * (HO * WO)
                              + (size_t)Hg0 * WO + Wg;

    float sreg[NLOAD];

    auto stage_load = [&](int cbase) {
        const float* fc = fbase + (size_t)cbase * HW;
        #pragma unroll
        for (int k = 0; k < NLOAD; ++k)
            sreg[k] = valid[k] ? fc[off[k]] : 0.f;
    };
    auto stage_write = [&](int buf) {
        #pragma unroll
        for (int k = 0; k < NLOAD; ++k)
            lds[buf][tid + k * 256] = sreg[k];
    };

    // Prologue: fill buffer 0.
    stage_load(c0);
    stage_write(0);
    __syncthreads();

    for (int g = 0; g < NGROUP; ++g) {
        const int buf = g & 1;

        // T14 split: issue next group's global loads BEFORE compute,
        // write them to LDS after — compute hides the HBM latency.
        if (g + 1 < NGROUP) stage_load(c0 + (g + 1) * UC);

        #pragma unroll
        for (int u = 0; u < UC; ++u) {
            const float* Lu = &lds[buf][u * CH_ELEMS];
            float acc0 = 0.f, acc1 = 0.f;
            #pragma unroll
            for (int ki = 0; ki < K; ++ki) {
                #pragma unroll
                for (int kj = 0; kj < K; ++kj) {
                    float f = Lu[(h_local + ki) * LDS_C + (w_local + kj)];
                    acc0 = fmaf(f, m0[ki * K + kj], acc0);
                    acc1 = fmaf(f, m1[ki * K + kj], acc1);
                }
            }
            float* oc = obase + (size_t)(c0 + g * UC + u) * (HO * WO);
            __builtin_nontemporal_store(acc0, oc);
            __builtin_nontemporal_store(acc1, oc + WO);
        }

        if (g + 1 < NGROUP) {
            stage_write(buf ^ 1);
            __syncthreads();
        }
    }
}

extern "C" void kernel_launch(void* const* d_in, const int* in_sizes, int n_in,
                              void* d_out, int out_size, void* d_ws, size_t ws_size,
                              hipStream_t stream) {
    const float* feat = (const float*)d_in[0];
    const float* mask = (const float*)d_in[1];
    float* out = (float*)d_out;

    dim3 grid(WO / (2 * WB), (HO / 2) / HB, N_ * (C_ / CCHUNK));  // (2, 16, 64)
    dim3 block(256);
    carafe_up_kernel<<<grid, block, 0, stream>>>(feat, mask, out);
}

// Round 3
// 50.833 us; speedup vs baseline: 1.4321x; 1.0572x over previous
//
#include <hip/hip_runtime.h>

#define K 5
#define N_ 8
#define C_ 256
#define H_ 64
#define W_ 64
#define HW (H_ * W_)
#define HO 128
#define WO 128
#define HOWO (HO * WO)
#define HB 4              // base rows per block
#define WB 32             // base cols per block
#define CCHUNK 32         // channels per block
#define UC 8              // channels per stage group (2 float4 slabs)
#define NGROUP (CCHUNK / UC)      // 4
#define LDS_R (HB + K - 1)        // 8
#define LDS_C (WB + K - 1)        // 36
#define POS (LDS_R * LDS_C)       // 288 spatial positions per tile

__global__ __launch_bounds__(256)
void carafe_up_kernel(const float* __restrict__ feat,
                      const float* __restrict__ mask,
                      float* __restrict__ out) {
    const int wt = blockIdx.x;           // 0..1   (W tile)
    const int ht = blockIdx.y;           // 0..15  (H tile)
    const int zc = blockIdx.z;           // 0..63  (n * 8 + chunk)
    const int n  = zc >> 3;
    const int c0 = (zc & 7) * CCHUNK;
    const int h0 = ht * HB;
    const int w0 = wt * WB;

    const int tid        = threadIdx.x;
    const int wlocal_out = tid & 63;     // output col within tile (0..63)
    const int h_local    = tid >> 6;     // base row within tile (0..3)
    const int w_local    = wlocal_out >> 1;
    const int Wg         = w0 * 2 + wlocal_out;
    const int Hg0        = (h0 + h_local) * 2;

    // Channel-invariant masks for this thread's two output pixels.
    float m0[K * K], m1[K * K];
    const float* mbase = mask + (size_t)n * (K * K) * HOWO
                              + (size_t)Hg0 * WO + Wg;
    #pragma unroll
    for (int i = 0; i < K * K; ++i) {
        m0[i] = mbase[(size_t)i * HOWO];
        m1[i] = mbase[(size_t)i * HOWO + WO];
    }

    // Staging geometry: each thread owns spatial pos tid (+256 for tid<32).
    int off0, off1;
    bool v0, v1, has1;
    {
        int p  = tid;
        int r  = p / LDS_C, cc = p - r * LDS_C;
        int hs = h0 - 2 + r, ws = w0 - 2 + cc;
        v0   = (hs >= 0 && hs < H_ && ws >= 0 && ws < W_);
        off0 = hs * W_ + ws;
    }
    has1 = (tid + 256) < POS;
    {
        int p  = tid + 256;
        int r  = p / LDS_C, cc = p - r * LDS_C;
        int hs = h0 - 2 + r, ws = w0 - 2 + cc;
        v1   = has1 && (hs >= 0 && hs < H_ && ws >= 0 && ws < W_);
        off1 = hs * W_ + ws;
    }

    // Channel-interleaved tile: [buf][slab of 4ch][pos] as float4.
    __shared__ float4 lds[2][2][POS];   // 18432 B

    const float* fbase = feat + (size_t)n * C_ * HW;
    float*       obase = out  + (size_t)n * C_ * HOWO
                              + (size_t)Hg0 * WO + Wg;

    float s0[UC], s1[UC];
    auto stage_load = [&](int cbase) {
        const float* fp = fbase + (size_t)cbase * HW;
        #pragma unroll
        for (int u = 0; u < UC; ++u) s0[u] = v0 ? fp[u * HW + off0] : 0.f;
        #pragma unroll
        for (int u = 0; u < UC; ++u) s1[u] = v1 ? fp[u * HW + off1] : 0.f;
    };
    auto stage_write = [&](int buf) {
        lds[buf][0][tid] = make_float4(s0[0], s0[1], s0[2], s0[3]);
        lds[buf][1][tid] = make_float4(s0[4], s0[5], s0[6], s0[7]);
        if (has1) {
            lds[buf][0][tid + 256] = make_float4(s1[0], s1[1], s1[2], s1[3]);
            lds[buf][1][tid + 256] = make_float4(s1[4], s1[5], s1[6], s1[7]);
        }
    };

    stage_load(c0);
    stage_write(0);
    __syncthreads();

    const int rbase = h_local * LDS_C + w_local;   // tap (0,0) position

    for (int g = 0; g < NGROUP; ++g) {
        const int buf = g & 1;

        // T14: issue next group's global loads before compute.
        if (g + 1 < NGROUP) stage_load(c0 + (g + 1) * UC);

        #pragma unroll
        for (int s = 0; s < 2; ++s) {
            const float4* Ls = &lds[buf][s][rbase];
            float a0x = 0.f, a0y = 0.f, a0z = 0.f, a0w = 0.f;
            float a1x = 0.f, a1y = 0.f, a1z = 0.f, a1w = 0.f;
            #pragma unroll
            for (int ki = 0; ki < K; ++ki) {
                #pragma unroll
                for (int kj = 0; kj < K; ++kj) {
                    float4 f  = Ls[ki * LDS_C + kj];   // 1 ds_read_b128
                    float  w0m = m0[ki * K + kj];
                    float  w1m = m1[ki * K + kj];
                    a0x = fmaf(f.x, w0m, a0x);  a1x = fmaf(f.x, w1m, a1x);
                    a0y = fmaf(f.y, w0m, a0y);  a1y = fmaf(f.y, w1m, a1y);
                    a0z = fmaf(f.z, w0m, a0z);  a1z = fmaf(f.z, w1m, a1z);
                    a0w = fmaf(f.w, w0m, a0w);  a1w = fmaf(f.w, w1m, a1w);
                }
            }
            float* oc = obase + (size_t)(c0 + g * UC + s * 4) * HOWO;
            __builtin_nontemporal_store(a0x, oc);
            __builtin_nontemporal_store(a1x, oc + WO);
            oc += HOWO;
            __builtin_nontemporal_store(a0y, oc);
            __builtin_nontemporal_store(a1y, oc + WO);
            oc += HOWO;
            __builtin_nontemporal_store(a0z, oc);
            __builtin_nontemporal_store(a1z, oc + WO);
            oc += HOWO;
            __builtin_nontemporal_store(a0w, oc);
            __builtin_nontemporal_store(a1w, oc + WO);
        }

        if (g + 1 < NGROUP) {
            stage_write(buf ^ 1);
            __syncthreads();
        }
    }
}

extern "C" void kernel_launch(void* const* d_in, const int* in_sizes, int n_in,
                              void* d_out, int out_size, void* d_ws, size_t ws_size,
                              hipStream_t stream) {
    const float* feat = (const float*)d_in[0];
    const float* mask = (const float*)d_in[1];
    float* out = (float*)d_out;

    dim3 grid(WO / (2 * WB), (HO / 2) / HB, N_ * (C_ / CCHUNK));  // (2, 16, 64)
    dim3 block(256);
    carafe_up_kernel<<<grid, block, 0, stream>>>(feat, mask, out);
}

// Round 4
// 45.903 us; speedup vs baseline: 1.5859x; 1.1074x over previous
//
#include <hip/hip_runtime.h>

#define K 5
#define N_ 8
#define C_ 256
#define H_ 64
#define W_ 64
#define HW (H_ * W_)
#define HO 128
#define WO 128
#define HOWO (HO * WO)
#define HB 8              // base rows per block
#define WB 32             // base cols per block
#define CCHUNK 32         // channels per block
#define UC 8              // channels per stage group (2 float4 slabs)
#define NGROUP (CCHUNK / UC)      // 4
#define LDS_R (HB + K - 1)        // 12
#define LDS_C (WB + K - 1)        // 36
#define POS (LDS_R * LDS_C)       // 432

typedef __attribute__((ext_vector_type(2))) float f2;

__global__ __launch_bounds__(256)
void carafe_quad_kernel(const float* __restrict__ feat,
                        const float* __restrict__ mask,
                        float* __restrict__ out) {
    const int wt = blockIdx.x;       // 0..1
    const int ht = blockIdx.y;       // 0..7
    const int zc = blockIdx.z;       // 0..63  (n*8 + chunk)
    const int n  = zc >> 3;
    const int c0 = (zc & 7) * CCHUNK;
    const int h0 = ht * HB;
    const int w0 = wt * WB;

    const int tid = threadIdx.x;
    const int r   = tid >> 5;        // 0..7  base row in tile
    const int c   = tid & 31;        // 0..31 base col in tile
    const int hb  = h0 + r;          // global base row
    const int wb  = w0 + c;          // global base col

    // Each thread owns the full 2x2 output quad of base pixel (hb,wb):
    // all 4 outputs share the SAME 5x5 feature window. Masks packed as
    // float2 over b (contiguous), per output row a.
    f2 m0[K * K], m1[K * K];
    {
        const f2* mb = (const f2*)(mask + (size_t)n * (K * K) * HOWO
                                        + (size_t)(2 * hb) * WO + 2 * wb);
        #pragma unroll
        for (int i = 0; i < K * K; ++i) {
            m0[i] = mb[(size_t)i * (HOWO / 2)];            // a = 0
            m1[i] = mb[(size_t)i * (HOWO / 2) + WO / 2];   // a = 1
        }
    }

    // Staging geometry: thread covers halo pos tid and tid+256 (if < POS).
    int off0, off1;
    bool v0, v1, has1;
    {
        int p  = tid;
        int rr = p / LDS_C, cc = p - rr * LDS_C;
        int hs = h0 - 2 + rr, ws = w0 - 2 + cc;
        v0   = (hs >= 0 && hs < H_ && ws >= 0 && ws < W_);
        off0 = hs * W_ + ws;
    }
    has1 = (tid + 256) < POS;
    {
        int p  = tid + 256;
        int rr = p / LDS_C, cc = p - rr * LDS_C;
        int hs = h0 - 2 + rr, ws = w0 - 2 + cc;
        v1   = has1 && (hs >= 0 && hs < H_ && ws >= 0 && ws < W_);
        off1 = hs * W_ + ws;
    }

    // Channel-interleaved halo tile: [buf][slab of 4ch][pos] as float4.
    __shared__ float4 lds[2][2][POS];   // 27648 B

    const float* fbase = feat + (size_t)n * C_ * HW;
    float*       obase = out  + (size_t)n * C_ * HOWO
                              + (size_t)(2 * hb) * WO + 2 * wb;

    float s0[UC], s1[UC];
    auto stage_load = [&](int cbase) {
        const float* fp = fbase + (size_t)cbase * HW;
        #pragma unroll
        for (int u = 0; u < UC; ++u) s0[u] = v0 ? fp[u * HW + off0] : 0.f;
        #pragma unroll
        for (int u = 0; u < UC; ++u) s1[u] = v1 ? fp[u * HW + off1] : 0.f;
    };
    auto stage_write = [&](int buf) {
        lds[buf][0][tid] = make_float4(s0[0], s0[1], s0[2], s0[3]);
        lds[buf][1][tid] = make_float4(s0[4], s0[5], s0[6], s0[7]);
        if (has1) {
            lds[buf][0][tid + 256] = make_float4(s1[0], s1[1], s1[2], s1[3]);
            lds[buf][1][tid + 256] = make_float4(s1[4], s1[5], s1[6], s1[7]);
        }
    };

    stage_load(c0);
    stage_write(0);
    __syncthreads();

    const int rbase = r * LDS_C + c;    // tap (0,0) halo position

    for (int g = 0; g < NGROUP; ++g) {
        const int buf = g & 1;

        // T14: issue next group's global loads before compute.
        if (g + 1 < NGROUP) stage_load(c0 + (g + 1) * UC);

        #pragma unroll
        for (int s = 0; s < 2; ++s) {
            const float4* Ls = &lds[buf][s][rbase];
            f2 a0[4], a1[4];
            #pragma unroll
            for (int u = 0; u < 4; ++u) { a0[u] = (f2)0.f; a1[u] = (f2)0.f; }
            #pragma unroll
            for (int ki = 0; ki < K; ++ki) {
                #pragma unroll
                for (int kj = 0; kj < K; ++kj) {
                    float4 f  = Ls[ki * LDS_C + kj];   // 1 ds_read_b128 -> 16 FMA
                    f2 w0m = m0[ki * K + kj];
                    f2 w1m = m1[ki * K + kj];
                    a0[0] += f.x * w0m;  a1[0] += f.x * w1m;
                    a0[1] += f.y * w0m;  a1[1] += f.y * w1m;
                    a0[2] += f.z * w0m;  a1[2] += f.z * w1m;
                    a0[3] += f.w * w0m;  a1[3] += f.w * w1m;
                }
            }
            #pragma unroll
            for (int u = 0; u < 4; ++u) {
                f2* op = (f2*)(obase + (size_t)(c0 + g * UC + s * 4 + u) * HOWO);
                __builtin_nontemporal_store(a0[u], op);            // row 2hb,   cols 2wb..+1
                __builtin_nontemporal_store(a1[u], op + WO / 2);   // row 2hb+1
            }
        }

        if (g + 1 < NGROUP) {
            stage_write(buf ^ 1);
            __syncthreads();
        }
    }
}

extern "C" void kernel_launch(void* const* d_in, const int* in_sizes, int n_in,
                              void* d_out, int out_size, void* d_ws, size_t ws_size,
                              hipStream_t stream) {
    const float* feat = (const float*)d_in[0];
    const float* mask = (const float*)d_in[1];
    float* out = (float*)d_out;

    dim3 grid(W_ / WB, H_ / HB, N_ * (C_ / CCHUNK));  // (2, 8, 64)
    dim3 block(256);
    carafe_quad_kernel<<<grid, block, 0, stream>>>(feat, mask, out);
}